// Round 5
// baseline (235.973 us; speedup 1.0000x reference)
//
#include <hip/hip_runtime.h>

#define B_ 4
#define L_ 4096
#define D_ 1024
#define N_ 64

typedef _Float16 f16;
typedef __attribute__((ext_vector_type(8))) _Float16 half8;
typedef __attribute__((ext_vector_type(4))) float f32x4;

__device__ __forceinline__ float softplus_f(float x) {
    return fmaxf(x, 0.0f) + log1pf(__expf(-fabsf(x)));
}

__device__ __forceinline__ float tanh_f(float x) {
    float xc = fminf(fmaxf(x, -15.0f), 15.0f);
    float e = __expf(2.0f * xc);
    return (e - 1.0f) / (e + 1.0f);
}

// ---------------------------------------------------------------------------
// Prep: WT [192][1024] fp16 (rows 0-127 = Wp cols, 128-191 = Ws cols);
// WoT [1024][64] fp16 (WoT[d][n] = Wo[n][d]).
// ---------------------------------------------------------------------------
__global__ __launch_bounds__(256) void k_prepw(
    const float* __restrict__ Wp, const float* __restrict__ Ws,
    const float* __restrict__ Wo, f16* __restrict__ WT, f16* __restrict__ WoT)
{
    int gid = blockIdx.x * 256 + threadIdx.x;
    if (gid < 24576) {
        int r = gid >> 7, kg = gid & 127;
        const float* src; int ncol, c;
        if (r < 128) { src = Wp; ncol = 128; c = r; }
        else         { src = Ws; ncol = 64;  c = r - 128; }
        f16 h[8];
        #pragma unroll
        for (int j = 0; j < 8; j++)
            h[j] = (f16)src[(size_t)(kg * 8 + j) * ncol + c];
        *(uint4*)&WT[(size_t)r * 1024 + kg * 8] = *(uint4*)h;
    } else {
        int g2 = gid - 24576;                 // < 8192
        int d = g2 >> 3, ng = g2 & 7;
        f16 h[8];
        #pragma unroll
        for (int j = 0; j < 8; j++)
            h[j] = (f16)Wo[(size_t)(ng * 8 + j) * D_ + d];
        *(uint4*)&WoT[(size_t)d * 64 + ng * 8] = *(uint4*)h;
    }
}

// ---------------------------------------------------------------------------
// Fused frontend: block (256 thr / 4 waves) = 32 tokens x 192 cols.
// cols 0-63: Bt, 64-127: Ct, 128-191: u. Wave w -> cols w*48..+47.
// Pipeline per 64-K chunk: shared conv tile (computed once), x double-buffer
// with register prefetch, WT register double-buffer. conv_w/b in LDS (once).
// Epilogue: z = dt*Bt*u, writes zT/cT n-major fp16.
// ---------------------------------------------------------------------------
__global__ __launch_bounds__(256) void k_frontend(
    const float* __restrict__ x, const float* __restrict__ conv_w,
    const float* __restrict__ conv_b, const f16* __restrict__ WT,
    const float* __restrict__ bp, const float* __restrict__ bs,
    const float* __restrict__ dt_log,
    f16* __restrict__ zT, f16* __restrict__ cT)
{
    __shared__ float cwS[4 * 1024];             // 16 KB conv_w
    __shared__ float cbS[1024];                 // 4 KB  conv_b
    __shared__ __align__(16) f16 xh[2][36 * 72];// 10.1 KB x chunks (dbuf)
    __shared__ __align__(16) f16 cvh[32 * 72];  // 4.5 KB conv tile
    __shared__ float sE[3 * 32 * 68];           // 26.1 KB epilogue

    const int tid = threadIdx.x;
    const int w = tid >> 6, lane = tid & 63;
    const int r = lane & 15, q = lane >> 4;
    const int T0 = blockIdx.x * 32;
    const int bb = T0 >> 12;
    const int l0 = T0 & (L_ - 1);
    const int cw0 = w * 48;

    f32x4 acc[3][2] = {};
    float4 rA[3];
    half8 wt[2][3][2];

    #define LDX(c0)                                                          \
        {                                                                    \
            _Pragma("unroll")                                                \
            for (int s = 0; s < 3; s++) {                                    \
                int idx = tid + 256 * s;                                     \
                float4 v = make_float4(0.f, 0.f, 0.f, 0.f);                  \
                if (idx < 576) {                                             \
                    int row = idx >> 4, g = idx & 15;                        \
                    int l = l0 + row - 4;                                    \
                    if (l >= 0)                                              \
                        v = *(const float4*)&x[((size_t)(bb * L_ + l)) * D_  \
                                               + (c0) + g * 4];              \
                }                                                            \
                rA[s] = v;                                                   \
            }                                                                \
        }

    #define STX(buf)                                                         \
        {                                                                    \
            _Pragma("unroll")                                                \
            for (int s = 0; s < 3; s++) {                                    \
                int idx = tid + 256 * s;                                     \
                if (idx < 576) {                                             \
                    int row = idx >> 4, g = idx & 15;                        \
                    f16 h[4] = {(f16)rA[s].x, (f16)rA[s].y,                  \
                                (f16)rA[s].z, (f16)rA[s].w};                 \
                    *(uint2*)&xh[buf][row * 72 + g * 4] = *(uint2*)h;        \
                }                                                            \
            }                                                                \
        }

    #define LDWT(buf, cc)                                                    \
        {                                                                    \
            const int kb = (cc) * 64;                                        \
            _Pragma("unroll")                                                \
            for (int mf = 0; mf < 3; mf++)                                   \
                _Pragma("unroll")                                            \
                for (int ks = 0; ks < 2; ks++)                               \
                    wt[buf][mf][ks] = *(const half8*)&WT[                    \
                        (size_t)(cw0 + mf * 16 + r) * 1024 + kb + ks * 32 +  \
                        q * 8];                                              \
        }

    // one-time staging: conv weights + bias to LDS
    for (int idx = tid; idx < 1024; idx += 256)
        *(float4*)&cwS[idx * 4] = *(const float4*)&conv_w[idx * 4];
    for (int idx = tid; idx < 256; idx += 256)
        *(float4*)&cbS[idx * 4] = *(const float4*)&conv_b[idx * 4];

    LDX(0);
    STX(0);
    LDX(64);
    LDWT(0, 0);
    __syncthreads();

    for (int c = 0; c < 16; c++) {
        const int cur = c & 1;
        // cooperative conv tile: t = tid>>3 (0..31), kg = tid&7
        {
            const int t = tid >> 3, kg = tid & 7;
            const int kb = c * 64 + kg * 8;
            float4 w3a = *(const float4*)&cwS[3 * 1024 + kb];
            float4 w3b = *(const float4*)&cwS[3 * 1024 + kb + 4];
            float4 w2a = *(const float4*)&cwS[2 * 1024 + kb];
            float4 w2b = *(const float4*)&cwS[2 * 1024 + kb + 4];
            float4 w1a = *(const float4*)&cwS[1 * 1024 + kb];
            float4 w1b = *(const float4*)&cwS[1 * 1024 + kb + 4];
            float4 w0a = *(const float4*)&cwS[0 * 1024 + kb];
            float4 w0b = *(const float4*)&cwS[0 * 1024 + kb + 4];
            float4 cba = *(const float4*)&cbS[kb];
            float4 cbb = *(const float4*)&cbS[kb + 4];
            half8 x0 = *(const half8*)&xh[cur][(t + 4) * 72 + kg * 8];
            half8 x1 = *(const half8*)&xh[cur][(t + 3) * 72 + kg * 8];
            half8 x2 = *(const half8*)&xh[cur][(t + 2) * 72 + kg * 8];
            half8 x3 = *(const half8*)&xh[cur][(t + 1) * 72 + kg * 8];
            float w3v[8] = {w3a.x,w3a.y,w3a.z,w3a.w,w3b.x,w3b.y,w3b.z,w3b.w};
            float w2v[8] = {w2a.x,w2a.y,w2a.z,w2a.w,w2b.x,w2b.y,w2b.z,w2b.w};
            float w1v[8] = {w1a.x,w1a.y,w1a.z,w1a.w,w1b.x,w1b.y,w1b.z,w1b.w};
            float w0v[8] = {w0a.x,w0a.y,w0a.z,w0a.w,w0b.x,w0b.y,w0b.z,w0b.w};
            float cbv[8] = {cba.x,cba.y,cba.z,cba.w,cbb.x,cbb.y,cbb.z,cbb.w};
            half8 hc;
            #pragma unroll
            for (int u = 0; u < 8; u++) {
                float s0 = cbv[u];
                s0 = fmaf(w3v[u], (float)x0[u], s0);
                s0 = fmaf(w2v[u], (float)x1[u], s0);
                s0 = fmaf(w1v[u], (float)x2[u], s0);
                s0 = fmaf(w0v[u], (float)x3[u], s0);
                hc[u] = (f16)s0;
            }
            *(uint4*)&cvh[t * 72 + kg * 8] = *(uint4*)&hc;
        }
        __syncthreads();                       // conv tile ready

        if (c < 15) LDWT(1 - cur, c + 1);      // prefetch next WT

        #pragma unroll
        for (int ks = 0; ks < 2; ks++) {
            const int kl = ks * 32 + q * 8;
            half8 braw[2], bcnv[2];
            #pragma unroll
            for (int nf = 0; nf < 2; nf++) {
                braw[nf] = *(const half8*)&xh[cur][(nf * 16 + r + 4) * 72 + kl];
                bcnv[nf] = *(const half8*)&cvh[(nf * 16 + r) * 72 + kl];
            }
            #pragma unroll
            for (int mf = 0; mf < 3; mf++) {
                const bool useConv = (cw0 + mf * 16) < 128;
                #pragma unroll
                for (int nf = 0; nf < 2; nf++)
                    acc[mf][nf] = __builtin_amdgcn_mfma_f32_16x16x32_f16(
                        wt[cur][mf][ks], useConv ? bcnv[nf] : braw[nf],
                        acc[mf][nf], 0, 0, 0);
            }
        }

        if (c < 15) STX(1 - cur);              // rA holds chunk c+1
        if (c < 14) LDX((c + 2) * 64);
        __syncthreads();                       // next x/conv safe
    }

    // --- epilogue: bias + activation -> sE ---
    float* sB = sE;
    float* sC = sE + 32 * 68;
    float* sU = sE + 2 * 32 * 68;
    #pragma unroll
    for (int mf = 0; mf < 3; mf++) {
        const int cb4 = cw0 + mf * 16 + q * 4;
        const int seg = cb4 >> 6;
        const int cl = cb4 & 63;
        const float4 bb4 = (seg == 2) ? *(const float4*)&bs[cl]
                                      : *(const float4*)&bp[cb4];
        float* dst = (seg == 0) ? sB : (seg == 1 ? sC : sU);
        #pragma unroll
        for (int nf = 0; nf < 2; nf++) {
            const int t = nf * 16 + r;
            float v0 = acc[mf][nf][0] + bb4.x;
            float v1 = acc[mf][nf][1] + bb4.y;
            float v2 = acc[mf][nf][2] + bb4.z;
            float v3 = acc[mf][nf][3] + bb4.w;
            if (seg == 0) {
                v0 = softplus_f(v0); v1 = softplus_f(v1);
                v2 = softplus_f(v2); v3 = softplus_f(v3);
            } else if (seg == 1) {
                v0 = tanh_f(v0); v1 = tanh_f(v1);
                v2 = tanh_f(v2); v3 = tanh_f(v3);
            }
            float4 vv = {v0, v1, v2, v3};
            *(float4*)&dst[t * 68 + cl] = vv;
        }
    }
    __syncthreads();

    // --- fused combine: z = dt[n]*Bt*u, store zT/cT n-major ---
    {
        const int n = tid >> 2, tg = tid & 3;
        const float dtv = softplus_f(dt_log[n]);
        f16 hz[8], hc[8];
        #pragma unroll
        for (int j = 0; j < 8; j++) {
            const int t = tg * 8 + j;
            hz[j] = (f16)(dtv * sB[t * 68 + n] * sU[t * 68 + n]);
            hc[j] = (f16)sC[t * 68 + n];
        }
        size_t o = ((size_t)(bb * N_ + n)) * L_ + l0 + tg * 8;
        *(uint4*)&zT[o] = *(uint4*)hz;
        *(uint4*)&cT[o] = *(uint4*)hc;
    }
    #undef LDX
    #undef STX
    #undef LDWT
}

// ---------------------------------------------------------------------------
// Scan: one block (256 thr / 4 waves) per (b,n) chain; register-resident.
// Lane handles 16 tokens; wave affine scan; cross-wave stitch via 4 floats.
// ---------------------------------------------------------------------------
__global__ __launch_bounds__(256) void k_scan(
    const f16* __restrict__ zT, const f16* __restrict__ cT,
    const float* __restrict__ A_log, const float* __restrict__ dt_log,
    f16* __restrict__ yH)
{
    __shared__ float Tw[4];
    const int bn = blockIdx.x;
    const int n = bn & (N_ - 1);
    const int tid = threadIdx.x;
    const int w = tid >> 6, lane = tid & 63;
    const size_t base = (size_t)bn * L_ + tid * 16;

    uint4 uz0 = *(const uint4*)(zT + base);
    uint4 uz1 = *(const uint4*)(zT + base + 8);
    uint4 uc0 = *(const uint4*)(cT + base);
    uint4 uc1 = *(const uint4*)(cT + base + 8);

    float z[16], cc[16];
    {
        const f16* hz0 = (const f16*)&uz0;
        const f16* hz1 = (const f16*)&uz1;
        const f16* hc0 = (const f16*)&uc0;
        const f16* hc1 = (const f16*)&uc1;
        #pragma unroll
        for (int j = 0; j < 8; j++) {
            z[j] = (float)hz0[j]; z[8 + j] = (float)hz1[j];
            cc[j] = (float)hc0[j]; cc[8 + j] = (float)hc1[j];
        }
    }

    const float dtv = softplus_f(dt_log[n]);
    const float Av = -softplus_f(A_log[n]);
    const float dec = fmaf(dtv, Av, 1.0f);

    // local 16-step scan (zero init)
    float s = 0.0f;
    #pragma unroll
    for (int j = 0; j < 16; j++) s = fmaf(dec, s, z[j]);

    const float d2 = dec * dec, d4 = d2 * d2, d8 = d4 * d4, a16 = d8 * d8;

    // wave affine scan: f(x) = a16*x + e
    float Ag = a16, Bg = s;
    #pragma unroll
    for (int off = 1; off < 64; off <<= 1) {
        float Ap = __shfl_up(Ag, off);
        float Bp = __shfl_up(Bg, off);
        if (lane >= off) { Bg = fmaf(Ag, Bp, Bg); Ag *= Ap; }
    }
    float twv = __shfl(Bg, 63);
    if (lane == 0) Tw[w] = twv;
    __syncthreads();

    // a1024 = a16^64
    float a32 = a16 * a16, a64 = a32 * a32, a128 = a64 * a64;
    float a256 = a128 * a128, a512 = a256 * a256, a1024 = a512 * a512;

    float S = 0.0f;
    for (int v = 0; v < w; v++) S = fmaf(a1024, S, Tw[v]);

    float cl = __shfl_up(Bg, 1);
    if (lane == 0) cl = 0.0f;

    // a16^lane by binary powering
    float p = 1.0f, bpow = a16;
    int e = lane;
    #pragma unroll
    for (int bit = 0; bit < 6; bit++) {
        if (e & 1) p *= bpow;
        bpow *= bpow;
        e >>= 1;
    }

    float st = fmaf(S, p, cl);
    f16 hy[16];
    #pragma unroll
    for (int j = 0; j < 16; j++) {
        st = fmaf(dec, st, z[j]);
        hy[j] = (f16)(cc[j] * st);
    }
    *(uint4*)(yH + base) = *(uint4*)&hy[0];
    *(uint4*)(yH + base + 8) = *(uint4*)&hy[8];
}

// ---------------------------------------------------------------------------
// Out GEMM: out[t][d] = y[t][:] @ Wo[:,d] + bo.  A = WoT (m=d), B = y.
// Block 256 thr: 64 tok x 128 d; WoT loads issued before LDS staging.
// ---------------------------------------------------------------------------
__global__ __launch_bounds__(256) void k_out(
    const f16* __restrict__ yH, const f16* __restrict__ WoT,
    const float* __restrict__ bo, float* __restrict__ out)
{
    __shared__ __align__(16) f16 ys[64 * 72];
    const int tid = threadIdx.x;
    const int w = tid >> 6, lane = tid & 63;
    const int r = lane & 15, q = lane >> 4;
    const int T0 = blockIdx.x * 64;
    const int bb = T0 >> 12, l0 = T0 & (L_ - 1);
    const int dw = blockIdx.y * 128 + w * 32;

    // issue WoT loads first (independent of staging)
    half8 af[2][2];
    #pragma unroll
    for (int ks = 0; ks < 2; ks++)
        #pragma unroll
        for (int mf = 0; mf < 2; mf++)
            af[ks][mf] = *(const half8*)&WoT[(size_t)(dw + mf * 16 + r) * 64 +
                                             ks * 32 + q * 8];

    // stage y transpose: [n-major global] -> ys[t][n]
    {
        const int n = tid & 63, tg = tid >> 6;
        #pragma unroll
        for (int h2 = 0; h2 < 2; h2++) {
            uint4 v = *(const uint4*)&yH[((size_t)(bb * N_ + n)) * L_ + l0 +
                                         tg * 16 + h2 * 8];
            const f16* hh = (const f16*)&v;
            #pragma unroll
            for (int j = 0; j < 8; j++)
                ys[(tg * 16 + h2 * 8 + j) * 72 + n] = hh[j];
        }
    }
    __syncthreads();

    f32x4 acc[2][4] = {};
    #pragma unroll
    for (int ks = 0; ks < 2; ks++) {
        const int kk = ks * 32 + q * 8;
        #pragma unroll
        for (int nf = 0; nf < 4; nf++) {
            half8 bf = *(const half8*)&ys[(nf * 16 + r) * 72 + kk];
            #pragma unroll
            for (int mf = 0; mf < 2; mf++)
                acc[mf][nf] = __builtin_amdgcn_mfma_f32_16x16x32_f16(
                    af[ks][mf], bf, acc[mf][nf], 0, 0, 0);
        }
    }

    #pragma unroll
    for (int mf = 0; mf < 2; mf++) {
        const int d = dw + mf * 16 + q * 4;
        const float4 bb4 = *(const float4*)&bo[d];
        #pragma unroll
        for (int nf = 0; nf < 4; nf++) {
            const int t = T0 + nf * 16 + r;
            float4 o = {acc[mf][nf][0] + bb4.x, acc[mf][nf][1] + bb4.y,
                        acc[mf][nf][2] + bb4.z, acc[mf][nf][3] + bb4.w};
            *(float4*)&out[(size_t)t * D_ + d] = o;
        }
    }
}

// ---------------------------------------------------------------------------
extern "C" void kernel_launch(void* const* d_in, const int* in_sizes, int n_in,
                              void* d_out, int out_size, void* d_ws, size_t ws_size,
                              hipStream_t stream) {
    const float* x      = (const float*)d_in[0];
    const float* conv_w = (const float*)d_in[1];
    const float* conv_b = (const float*)d_in[2];
    const float* Wp     = (const float*)d_in[3];
    const float* bp     = (const float*)d_in[4];
    const float* Ws     = (const float*)d_in[5];
    const float* bs     = (const float*)d_in[6];
    const float* A_log  = (const float*)d_in[7];
    const float* dt_log = (const float*)d_in[8];
    const float* Wo     = (const float*)d_in[9];
    const float* bo     = (const float*)d_in[10];
    float* out = (float*)d_out;

    char* wsp = (char*)d_ws;
    f16* WT  = (f16*)wsp;                     // 384 KB
    f16* WoT = (f16*)(wsp + 393216);          // 128 KB
    f16* zT  = (f16*)(wsp + 524288);          // 2 MB [B,N,L]
    f16* cT  = (f16*)(wsp + 2621440);         // 2 MB
    f16* yH  = (f16*)(wsp + 4718592);         // 2 MB

    k_prepw<<<dim3(128), dim3(256), 0, stream>>>(Wp, Ws, Wo, WT, WoT);
    k_frontend<<<dim3(B_ * L_ / 32), dim3(256), 0, stream>>>(
        x, conv_w, conv_b, WT, bp, bs, dt_log, zT, cT);
    k_scan<<<dim3(B_ * N_), dim3(256), 0, stream>>>(zT, cT, A_log, dt_log, yH);
    k_out<<<dim3(B_ * L_ / 64, D_ / 128), dim3(256), 0, stream>>>(yH, WoT, bo, out);
}